// Round 9
// baseline (718.548 us; speedup 1.0000x reference)
//
#include <hip/hip_runtime.h>
#include <hip/hip_bf16.h>

#define K_DIM 4096
#define N_DIM 4096
#define M_DIM 4096

typedef __attribute__((ext_vector_type(8)))  short bf16x8;    // 8 bf16, 4 VGPRs
typedef __attribute__((ext_vector_type(4)))  float f32x4;     // 16x16 MFMA acc
typedef __attribute__((ext_vector_type(16))) float f32x16;    // 32x32 MFMA acc (fallback)
typedef __attribute__((ext_vector_type(8)))  unsigned short u16x8;

// ---------- fp32 -> bf16 (round-to-nearest-even) ----------
__device__ __forceinline__ unsigned short f2bf(float f) {
    union { float f; unsigned int u; } v; v.f = f;
    unsigned int u = v.u;
    return (unsigned short)((u + 0x7fffu + ((u >> 16) & 1u)) >> 16);
}

// ---------- fused convert: x and W in one launch ----------
__global__ void cvt2_f32_to_bf16(const float* __restrict__ x,
                                 const float* __restrict__ W,
                                 unsigned short* __restrict__ xb,
                                 unsigned short* __restrict__ wb,
                                 int blocks_each) {
    int b = blockIdx.x;
    const float* src = x;
    unsigned short* dst = xb;
    if (b >= blocks_each) { b -= blocks_each; src = W; dst = wb; }
    const int i = (b * 256 + threadIdx.x) * 8;
    float4 f0 = *(const float4*)(src + i);
    float4 f1 = *(const float4*)(src + i + 4);
    u16x8 o;
    o[0] = f2bf(f0.x); o[1] = f2bf(f0.y); o[2] = f2bf(f0.z); o[3] = f2bf(f0.w);
    o[4] = f2bf(f1.x); o[5] = f2bf(f1.y); o[6] = f2bf(f1.z); o[7] = f2bf(f1.w);
    *(u16x8*)(dst + i) = o;
}

// ---------- async global->LDS, 16B per lane (dest = wave-uniform base + lane*16) ----------
__device__ __forceinline__ void gl_lds16(const void* g, void* l) {
    __builtin_amdgcn_global_load_lds(
        (const __attribute__((address_space(1))) void*)g,
        (__attribute__((address_space(3))) void*)l,
        16, 0, 0);
}

// ============================================================================
// V9: B (weights) moved OUT of LDS into global->register double-buffered
// prefetch; LDS stages A only (64 KiB).  Rationale: 8 rounds show K-tile time
// = LDS-read + MFMA, additive (~4650 cyc).  Removing B cuts LDS per K-tile
// from 192KB read + 64KB write to 128KB read + 32KB write (~1900 cyc),
// fitting under the 2480-cyc MFMA floor.
//  * 256x256 tile, BK=64, 8 waves, 16x16x32 MFMA, per-wave 128x64 out.
//  * B frags: per wave 8 x global_load_dwordx4 per K-tile = 16 full 64B
//    lines (lanes {l16, l16+16, l16+32, l16+48} cover one line); per-K-tile
//    B slice is L2-resident.  Issued one FULL K-tile early (~3000 cyc slack
//    vs ~200 cyc L2 latency); reg deps make the compiler insert the waits.
//  * Single compute window per K-tile, 2 barriers; read/MFMA interleave
//    pinned with sched_barrier(0); odd waves take k-windows in opposite
//    order (anti-phase -> the 2 waves/SIMD overlap read and MFMA bursts).
//  * vmcnt accounting (in-order retirement), steady state at stage point:
//    outstanding = A(t+1)4 + B(t+1)8 + A(t+2)4 = 16 -> vmcnt(12) retires
//    exactly A(t+1); B(t+1)/A(t+2) stay in flight (never 0 mid-loop).
//  * A LDS layout/swizzle unchanged from V1-V3 (granule slot q holds global
//    granule q ^ ((row>>1)&3); measured 0 bank conflicts).
// ============================================================================
__global__ __launch_bounds__(512, 2) void gemm256(
    const unsigned short* __restrict__ A,   // [M,K] bf16
    const unsigned short* __restrict__ B,   // [N,K] bf16
    const float* __restrict__ bias, float* __restrict__ C) {

    __shared__ __align__(16) unsigned short sh[32768];   // 64 KiB (A only)

    const int tid  = threadIdx.x;
    const int wave = tid >> 6;
    const int lane = tid & 63;
    const int l16  = lane & 15;
    const int gq   = lane >> 4;        // k-granule 0..3
    const int wm   = wave >> 2;        // 0..1  (M half of wave grid)
    const int wn   = wave & 3;         // 0..3  (N quarter)

    // XCD swizzle: 256 blocks over 8 XCDs; per-XCD 4x8 patch of 256^2 tiles.
    const int bid = blockIdx.x;
    const int xcd = bid & 7;
    const int idx = bid >> 3;                          // 0..31
    const int mt  = ((xcd >> 1) << 2) + (idx >> 3);    // 0..15
    const int nt  = ((xcd & 1) << 3) + (idx & 7);      // 0..15
    const size_t bm = (size_t)mt << 8;
    const size_t bn = (size_t)nt << 8;

    // ---- A staging: 512 thr x 16B; one stage() = one 16KB region (2 gl_lds)
    const int srow  = tid >> 2;                              // 0..127
    const int sg8   = ((tid & 3) ^ ((tid >> 3) & 3)) << 3;   // inverse-swizzled src granule
    const int wslot = wave << 9;                             // wave*512 shorts

    const unsigned short* Abase = A + bm * K_DIM;

    auto stage = [&](int dstbase, int kelem) {
        const unsigned short* s0 = Abase + (size_t)srow * K_DIM + kelem + sg8;
        gl_lds16(s0,                        &sh[dstbase + wslot]);
        gl_lds16(s0 + (size_t)128 * K_DIM,  &sh[dstbase + 4096 + wslot]);
    };

    // ---- A read-side: same 0-conflict pattern as V1-V3 (measured 0)
    const int koff = (gq ^ ((l16 >> 1) & 3)) << 3;           // shorts
    const int aoff = ((wm << 7) + l16) * 32 + koff;

    // ---- B frag base offset (shorts): col = bn + wn*64 + n*16 + l16, k = gq*8
    const unsigned int bvo0 = (unsigned int)((bn + wn * 64 + l16) * K_DIM + gq * 8);

    f32x4 acc[8][4] = {};      // 128 acc regs
    bf16x8 a0[4], a1[4];       // rotating A frag sets
    bf16x8 bE0[4], bE1[4], bO0[4], bO1[4];   // B k-window sets, E/O tile parity

#define RD_A(dst, base, fbase)                                                \
    _Pragma("unroll")                                                         \
    for (int f = 0; f < 4; f++)                                               \
        dst[f] = *(const bf16x8*)&sh[(base) + aoff + ((fbase) + f) * 512];

#define MM(FOFF, AS, BS)                                                      \
    __builtin_amdgcn_s_setprio(1);                                            \
    _Pragma("unroll")                                                         \
    for (int f = 0; f < 4; f++)                                               \
        _Pragma("unroll")                                                     \
        for (int n = 0; n < 4; n++)                                           \
            acc[f + FOFF][n] = __builtin_amdgcn_mfma_f32_16x16x32_bf16(       \
                AS[f], BS[n], acc[f + FOFF][n], 0, 0, 0);                     \
    __builtin_amdgcn_s_setprio(0);

// one K-tile compute window: first k-window (Xa,Ba) then second (Xb,Bb)
#define HALFSEQ(Xa, Xb, Ba, Bb)                                               \
    RD_A(a0, Xa, 0)                                                           \
    RD_A(a1, Xa, 4)                                                           \
    __builtin_amdgcn_sched_barrier(0);                                        \
    MM(0, a0, Ba)                                                             \
    __builtin_amdgcn_sched_barrier(0);                                        \
    RD_A(a0, Xb, 0)                                                           \
    MM(4, a1, Ba)                                                             \
    __builtin_amdgcn_sched_barrier(0);                                        \
    RD_A(a1, Xb, 4)                                                           \
    MM(0, a0, Bb)                                                             \
    __builtin_amdgcn_sched_barrier(0);                                        \
    MM(4, a1, Bb)

// stmode: 0 steady; 1 = t62 (B(63) issue, no A stage, drain); 2 = t63
#define KTILE(BC0, BC1, BN0, BN1, buf, t, stmode)                             \
    {                                                                         \
        const int X0 = (buf), X1 = (buf) + 8192;                              \
        if ((stmode) <= 1) {        /* prefetch B(t+1) into next sets */      \
            const unsigned int kofs = (unsigned int)((t) + 1) * 64;           \
            _Pragma("unroll")                                                 \
            for (int n = 0; n < 4; n++)                                       \
                BN0[n] = *(const bf16x8*)&B[(size_t)bvo0 + n * (16 * K_DIM) + kofs];        \
            _Pragma("unroll")                                                 \
            for (int n = 0; n < 4; n++)                                       \
                BN1[n] = *(const bf16x8*)&B[(size_t)bvo0 + n * (16 * K_DIM) + kofs + 32];   \
        }                                                                     \
        __builtin_amdgcn_sched_barrier(0);                                    \
        if (wave & 1) { HALFSEQ(X1, X0, BC1, BC0) }                           \
        else          { HALFSEQ(X0, X1, BC0, BC1) }                           \
        if ((stmode) != 2) {                                                  \
            __builtin_amdgcn_s_barrier();   /* all reads of buf consumed */   \
            if ((stmode) == 0) {            /* overwrite buf with A(t+2) */   \
                const int k2 = ((t) + 2) * 64;                                \
                stage(X0, k2);                                                \
                stage(X1, k2 + 32);                                           \
                asm volatile("s_waitcnt vmcnt(12)" ::: "memory");             \
            } else {                                                          \
                asm volatile("s_waitcnt vmcnt(0)" ::: "memory");              \
            }                                                                 \
            __builtin_amdgcn_s_barrier();   /* A(t+1) globally visible */     \
        }                                                                     \
    }

    // ---- prologue: A(t0)->buf0, A(t1)->buf1 (8 gl_lds); B(0) into E sets.
    // outstanding = A0(4) A1(4) B0(8) = 16; vmcnt(12) retires A(t0).
    stage(0,     0);
    stage(8192,  32);
    stage(16384, 64);
    stage(24576, 96);
#pragma unroll
    for (int n = 0; n < 4; n++)
        bE0[n] = *(const bf16x8*)&B[(size_t)bvo0 + n * (16 * K_DIM)];
#pragma unroll
    for (int n = 0; n < 4; n++)
        bE1[n] = *(const bf16x8*)&B[(size_t)bvo0 + n * (16 * K_DIM) + 32];
    asm volatile("s_waitcnt vmcnt(12)" ::: "memory");
    __builtin_amdgcn_s_barrier();

    for (int t = 0; t < 62; t += 2) {
        KTILE(bE0, bE1, bO0, bO1, 0,     t,     0)
        KTILE(bO0, bO1, bE0, bE1, 16384, t + 1, 0)
    }
    KTILE(bE0, bE1, bO0, bO1, 0,     62, 1)
    KTILE(bO0, bO1, bE0, bE1, 16384, 63, 2)
#undef KTILE
#undef HALFSEQ
#undef MM
#undef RD_A

    // ---- epilogue: 16x16 C/D layout: col = lane&15, row = (lane>>4)*4 + reg
    const size_t row0 = bm + (wm << 7) + (gq << 2);
    const size_t col0 = bn + (wn << 6) + l16;
#pragma unroll
    for (int n = 0; n < 4; n++) {
        const size_t col = col0 + n * 16;
        const float bv = bias[col];
#pragma unroll
        for (int f = 0; f < 8; f++) {
            const size_t r = row0 + f * 16;
#pragma unroll
            for (int j = 0; j < 4; j++)
                C[(r + j) * N_DIM + col] = acc[f][n][j] + bv;
        }
    }
}

// ============================================================================
// Fallback (no workspace): previous-session 128x128 fp32-input kernel, verbatim.
// ============================================================================
#define BM 128
#define BN 128
#define BK 32

__global__ __launch_bounds__(256) void gemm_bt_f32(
    const float* __restrict__ Aptr, const float* __restrict__ Bptr,
    const float* __restrict__ bias, float* __restrict__ C) {

    __shared__ __align__(16) unsigned short As[BM * BK];
    __shared__ __align__(16) unsigned short Bs[BN * BK];

    const int tid  = threadIdx.x;
    const int wave = tid >> 6;
    const int lane = tid & 63;
    const int r32  = lane & 31;
    const int hi   = lane >> 5;

    const int bid = blockIdx.x;
    const int xcd = bid & 7;
    const int idx = bid >> 3;
    const int mt  = ((xcd & 1) << 4) + (idx & 15);
    const int nt  = (((xcd >> 1) & 3) << 3) + (idx >> 4);
    const int bm  = mt * BM;
    const int bn  = nt * BN;

    const int wm = (wave & 1) * 64;
    const int wn = (wave >> 1) * 64;

    f32x16 acc[2][2] = {};
    const int sw = (r32 >> 1) & 3;

    for (int k0 = 0; k0 < K_DIM; k0 += BK) {
        __syncthreads();
        {
            const int r  = tid >> 1;
            const int q0 = (tid & 1) << 1;
            const int s  = (r >> 1) & 3;
            {
                const float* sp = &Aptr[(size_t)(bm + r) * K_DIM + k0 + (q0 << 3)];
                float4 f0 = *(const float4*)(sp + 0);
                float4 f1 = *(const float4*)(sp + 4);
                float4 f2 = *(const float4*)(sp + 8);
                float4 f3 = *(const float4*)(sp + 12);
                u16x8 o0, o1;
                o0[0]=f2bf(f0.x); o0[1]=f2bf(f0.y); o0[2]=f2bf(f0.z); o0[3]=f2bf(f0.w);
                o0[4]=f2bf(f1.x); o0[5]=f2bf(f1.y); o0[6]=f2bf(f1.z); o0[7]=f2bf(f1.w);
                o1[0]=f2bf(f2.x); o1[1]=f2bf(f2.y); o1[2]=f2bf(f2.z); o1[3]=f2bf(f2.w);
                o1[4]=f2bf(f3.x); o1[5]=f2bf(f3.y); o1[6]=f2bf(f3.z); o1[7]=f2bf(f3.w);
                *(u16x8*)&As[r * BK + ((q0 ^ s) << 3)]       = o0;
                *(u16x8*)&As[r * BK + (((q0 + 1) ^ s) << 3)] = o1;
            }
            {
                const float* sp = &Bptr[(size_t)(bn + r) * K_DIM + k0 + (q0 << 3)];
                float4 f0 = *(const float4*)(sp + 0);
                float4 f1 = *(const float4*)(sp + 4);
                float4 f2 = *(const float4*)(sp + 8);
                float4 f3 = *(const float4*)(sp + 12);
                u16x8 o0, o1;
                o0[0]=f2bf(f0.x); o0[1]=f2bf(f0.y); o0[2]=f2bf(f0.z); o0[3]=f2bf(f0.w);
                o0[4]=f2bf(f1.x); o0[5]=f2bf(f1.y); o0[6]=f2bf(f1.z); o0[7]=f2bf(f1.w);
                o1[0]=f2bf(f2.x); o1[1]=f2bf(f2.y); o1[2]=f2bf(f2.z); o1[3]=f2bf(f2.w);
                o1[4]=f2bf(f3.x); o1[5]=f2bf(f3.y); o1[6]=f2bf(f3.z); o1[7]=f2bf(f3.w);
                *(u16x8*)&Bs[r * BK + ((q0 ^ s) << 3)]       = o0;
                *(u16x8*)&Bs[r * BK + (((q0 + 1) ^ s) << 3)] = o1;
            }
        }
        __syncthreads();

        bf16x8 af[2][2], bfv[2][2];
#pragma unroll
        for (int t = 0; t < 2; t++)
#pragma unroll
            for (int h = 0; h < 2; h++) {
                const int koffl = (((hi + 2 * h) ^ sw)) << 3;
                af[t][h]  = *(const bf16x8*)&As[(wm + t * 32 + r32) * BK + koffl];
                bfv[t][h] = *(const bf16x8*)&Bs[(wn + t * 32 + r32) * BK + koffl];
            }
#pragma unroll
        for (int h = 0; h < 2; h++)
#pragma unroll
            for (int i = 0; i < 2; i++)
#pragma unroll
                for (int j = 0; j < 2; j++)
                    acc[i][j] = __builtin_amdgcn_mfma_f32_32x32x16_bf16(
                        af[i][h], bfv[j][h], acc[i][j], 0, 0, 0);
    }

#pragma unroll
    for (int i = 0; i < 2; i++) {
        const int rowb = bm + wm + i * 32 + 4 * hi;
#pragma unroll
        for (int j = 0; j < 2; j++) {
            const int col = bn + wn + j * 32 + r32;
            const float bv = bias[col];
#pragma unroll
            for (int reg = 0; reg < 16; reg++) {
                const int row = rowb + (reg & 3) + 8 * (reg >> 2);
                C[(size_t)row * N_DIM + col] = acc[i][j][reg] + bv;
            }
        }
    }
}

extern "C" void kernel_launch(void* const* d_in, const int* in_sizes, int n_in,
                              void* d_out, int out_size, void* d_ws, size_t ws_size,
                              hipStream_t stream) {
    const float* x = (const float*)d_in[0];   // [M, K]
    const float* W = (const float*)d_in[1];   // [N, K]
    const float* b = (const float*)d_in[2];   // [N]
    float* out = (float*)d_out;               // [M, N]

    const size_t elems = (size_t)M_DIM * K_DIM;
    const size_t need  = 2 * elems * sizeof(unsigned short);  // 64 MB

    if (ws_size >= need) {
        unsigned short* xb = (unsigned short*)d_ws;
        unsigned short* wb = xb + elems;
        const int blocks_each = (int)(elems / (256 * 8));     // 8192
        cvt2_f32_to_bf16<<<2 * blocks_each, 256, 0, stream>>>(x, W, xb, wb, blocks_each);
        dim3 grid((M_DIM / 256) * (N_DIM / 256));             // 256 blocks = 1/CU
        gemm256<<<grid, dim3(512), 0, stream>>>(xb, wb, b, out);
    } else {
        dim3 grid((M_DIM / BM) * (N_DIM / BN));
        gemm_bt_f32<<<grid, dim3(256), 0, stream>>>(x, W, b, out);
    }
}